// Round 4
// baseline (271.267 us; speedup 1.0000x reference)
//
#include <hip/hip_runtime.h>
#include <hip/hip_bf16.h>
#include <stdint.h>

typedef float v4f __attribute__((ext_vector_type(4)));
typedef short v8s __attribute__((ext_vector_type(8)));
typedef union { v8s v; unsigned u[4]; } v8u;

#define NB 40

__device__ __forceinline__ unsigned short f2b(float f) {
  __hip_bfloat16 h = __float2bfloat16(f);
  unsigned short u;
  __builtin_memcpy(&u, &h, 2);
  return u;
}
__device__ __forceinline__ unsigned pk2(float lo, float hi) {
  __hip_bfloat162 h = __float22bfloat162_rn(make_float2(lo, hi));
  unsigned u;
  __builtin_memcpy(&u, &h, 4);
  return u;
}
__device__ __forceinline__ float b2f16(unsigned short h) {
  return __uint_as_float(((unsigned)h) << 16);
}
__device__ __forceinline__ float blo(unsigned u) { return __uint_as_float(u << 16); }
__device__ __forceinline__ float bhi(unsigned u) { return __uint_as_float(u & 0xFFFF0000u); }

// ws layout (bytes):
//  A1pk   @ 0        : 12288     (2t x 3nt x 2ks A^T A-frags, zero n>=40 / m>=40)
//  W2pk   @ 12288    : 32768     (2t x 4ks x 4dt B-frags of gnn_w)
//  Gpk    @ 45056    : 245760    (80kt x 3jt A-frags of gate_w^T, K-order fl'=d*40+n)
//  s1     @ 290816   : 20480     s for f<64, [t][n][d] f32
//  sNT    @ 311296   : 20480+128 s for f>=64, [t][d][n] f32 (+pad)
//  bias2T @ 331904   : 20480     gnn_b + all-BN-offset fold, [t][d][n] f32
//  hLg    @ 352512   : 83886080  h' bf16 [b][t][d*40+n]  (d-major!)

// prep: params only. block 0: adjacency -> LN -> softmax -> A1pk (wave-parallel).
// blocks 1..63: everything else.  Gpk uses K-order fl' = d*40+n to match hLg.
__global__ __launch_bounds__(256) void prep(
    const float* __restrict__ masker,
    const float* __restrict__ ln_gamma, const float* __restrict__ ln_beta,
    const float* __restrict__ gnn_w, const float* __restrict__ gnn_b,
    const float* __restrict__ bn_gamma, const float* __restrict__ bn_beta,
    const float* __restrict__ bn_mean, const float* __restrict__ bn_var,
    const float* __restrict__ gate_w,
    unsigned short* __restrict__ A1pk, unsigned short* __restrict__ W2pk,
    unsigned short* __restrict__ Gpk, float* __restrict__ s1,
    float* __restrict__ sNT, float* __restrict__ bias2T)
{
  const int tid = threadIdx.x;
  if (blockIdx.x == 0) {
    __shared__ float AtL[2 * NB * NB];
    const int w = tid >> 6, lane = tid & 63;
    #pragma unroll 1
    for (int it = 0; it < 20; ++it) {
      const int c = it * 4 + w;        // 0..79
      const int t = c / NB, n = c % NB;
      const int m = lane;              // valid < 40
      float adj = 0.f;
      if (m < NB) {
        float p = masker[((t*3+0)*NB+m)*NB+n]
                * masker[((t*3+1)*NB+m)*NB+n]
                * masker[((t*3+2)*NB+m)*NB+n];
        adj = p > 0.f ? p : 0.f;
      }
      float s = adj;
      #pragma unroll
      for (int d = 1; d < 64; d <<= 1) s += __shfl_xor(s, d);
      const float mu = s * (1.f/NB);
      const float dv = (m < NB) ? adj - mu : 0.f;
      float v2 = dv * dv;
      #pragma unroll
      for (int d = 1; d < 64; d <<= 1) v2 += __shfl_xor(v2, d);
      const float inv = rsqrtf(v2 * (1.f/NB) + 1e-5f);
      float val = -3.0e38f;
      if (m < NB) {
        float lnv = dv * inv * ln_gamma[m] + ln_beta[m];
        val = lnv + (adj != 0.f ? 0.f : -1e9f) + (m == n ? 1.f : 0.f);
      }
      float mx = val;
      #pragma unroll
      for (int d = 1; d < 64; d <<= 1) mx = fmaxf(mx, __shfl_xor(mx, d));
      const float e = (m < NB) ? __expf(val - mx) : 0.f;
      float es = e;
      #pragma unroll
      for (int d = 1; d < 64; d <<= 1) es += __shfl_xor(es, d);
      if (m < NB)
        AtL[(t*NB+n)*NB + m] = (adj != 0.f) ? e / es : 0.f;
    }
    __syncthreads();
    for (int e = tid; e < 6144; e += 256) {
      int frag = e >> 9, rem = e & 511, lane2 = rem >> 3, jj = rem & 7;
      int t = frag / 6, r2 = frag % 6, nt = r2 >> 1, ks = r2 & 1;
      int n = nt*16 + (lane2 & 15);
      int m = ks*32 + (lane2 >> 4)*8 + jj;
      A1pk[e] = f2b((n < NB && m < NB) ? AtL[(t*NB+n)*NB+m] : 0.f);
    }
  } else {
    const int gid = (blockIdx.x - 1) * 256 + tid, gsz = 63 * 256;
    for (int e = gid; e < 16384; e += gsz) {
      int frag = e >> 9, rem = e & 511, lane = rem >> 3, jj = rem & 7;
      int t = frag >> 4, ks = (frag >> 2) & 3, dt = frag & 3;
      int f = ks*32 + (lane >> 4)*8 + jj, d = dt*16 + (lane & 15);
      W2pk[e] = f2b(gnn_w[t*8192 + f*64 + d]);
    }
    // Gpk: K-dim reordered fl' = d*40+n (matches d-major hLg)
    for (int e = gid; e < 122880; e += gsz) {
      int frag = e >> 9, rem = e & 511, lane = rem >> 3, jj = rem & 7;
      int kt = frag / 3, jt = frag % 3;
      int flp = kt*32 + (lane >> 4)*8 + jj;
      int dd = flp / 40, nn = flp - dd*40;
      int j = jt*16 + (lane & 15);
      Gpk[e] = f2b(j < NB ? gate_w[(nn*64 + dd)*NB + j] : 0.f);
    }
    for (int e = gid; e < 5120; e += gsz) {
      int t = e / 2560, n = (e % 2560) / 64, d = e & 63;
      int F = (t*NB + n)*128 + d;
      s1[e] = bn_gamma[F] * rsqrtf(bn_var[F] + 1e-5f);
    }
    for (int e = gid; e < 5120; e += gsz) {
      int t = e / 2560, d = (e % 2560) / 40, n = e % 40;
      int F = (t*NB + n)*128 + 64 + d;
      sNT[e] = bn_gamma[F] * rsqrtf(bn_var[F] + 1e-5f);
    }
    for (int e4 = gid; e4 < 20480; e4 += gsz) {
      int e = e4 >> 2, part = e4 & 3;
      int t = e / 2560, d = (e % 2560) / 40, n = e % 40;
      float acc = (part == 0) ? gnn_b[(t*NB + n)*64 + d] : 0.f;
      int Fb = (t*NB + n)*128;
      int f0 = part * 32;
      for (int f = f0; f < f0 + 32; ++f) {
        float s = bn_gamma[Fb+f] * rsqrtf(bn_var[Fb+f] + 1e-5f);
        float o = bn_beta[Fb+f] - bn_mean[Fb+f] * s;
        acc += o * gnn_w[t*8192 + f*64 + d];
      }
      acc += __shfl_xor(acc, 1);
      acc += __shfl_xor(acc, 2);
      if (part == 0) bias2T[e] = acc;
    }
  }
}

// kernelA: BARRIER-FREE. 4 waves/block, wave w owns batch b0+w end-to-end:
// phaseA (U=s1.*x) + x^T tile + GEMM1 (V=sNT.*A^T x) + GEMM2 -> hLg (d-major).
// All LDS regions are wave-private; same-wave DS ops execute in order, so no
// __syncthreads anywhere. LDS 47232 B -> 3 blocks/CU.
// Per-wave region (shorts): U[40][72] (2880) | V[40][72] (2880, x^T[64][42]
// overlays it during prologue). A-frag reads touch rows 40..47 -> overrun into
// the next region; values land in discarded output rows (+576-short tail pad).
__global__ __launch_bounds__(256) void kernelA(
    const float* __restrict__ x,
    const unsigned short* __restrict__ A1pk, const unsigned short* __restrict__ W2pk,
    const float* __restrict__ s1, const float* __restrict__ sNT,
    const float* __restrict__ bias2T, unsigned short* __restrict__ hLg)
{
  __shared__ __align__(16) unsigned short sh[4*5760 + 576];  // 47232 B

  const int tid = threadIdx.x;
  const int lane = tid & 63;
  const int w = tid >> 6;
  const int l15 = lane & 15, q = lane >> 4;
  const int b = blockIdx.x * 4 + w;

  unsigned short* Uw  = sh + w * 5760;
  unsigned short* Vw  = Uw + 2880;
  unsigned short* xTw = Vw;                       // x^T [64][42] overlays V

  const float* xb = x + (size_t)b * 2560;
  v8s b1[4][2];

  #pragma unroll 1
  for (int t = 0; t < 2; ++t) {
    // ---- Phase A: U = s1 .* x ; (t==0) also scatter raw x^T into xTw ----
    #pragma unroll
    for (int it = 0; it < 5; ++it) {
      const int n  = it*8 + (lane >> 3);
      const int f0 = (lane & 7) * 8;
      const float* xp = xb + n*64 + f0;
      const float4 fA = *(const float4*)xp;
      const float4 fB = *(const float4*)(xp + 4);
      const float* sp = s1 + (t*NB + n)*64 + f0;
      const float4 sA = *(const float4*)sp;
      const float4 sB = *(const float4*)(sp + 4);
      uint4 p;
      p.x = pk2(fA.x*sA.x, fA.y*sA.y);
      p.y = pk2(fA.z*sA.z, fA.w*sA.w);
      p.z = pk2(fB.x*sB.x, fB.y*sB.y);
      p.w = pk2(fB.z*sB.z, fB.w*sB.w);
      *(uint4*)(Uw + n*72 + f0) = p;
      if (t == 0) {
        xTw[(f0+0)*42 + n] = f2b(fA.x);
        xTw[(f0+1)*42 + n] = f2b(fA.y);
        xTw[(f0+2)*42 + n] = f2b(fA.z);
        xTw[(f0+3)*42 + n] = f2b(fA.w);
        xTw[(f0+4)*42 + n] = f2b(fB.x);
        xTw[(f0+5)*42 + n] = f2b(fB.y);
        xTw[(f0+6)*42 + n] = f2b(fB.z);
        xTw[(f0+7)*42 + n] = f2b(fB.w);
      }
    }
    // ---- (t==0) extract persistent GEMM1 B-frags from xTw ----
    if (t == 0) {
      #pragma unroll
      for (int dt = 0; dt < 4; ++dt) {
        const int r = dt*16 + l15;
        const unsigned* p0 = (const unsigned*)(xTw + r*42 + q*8);
        v8u u0;
        u0.u[0] = p0[0]; u0.u[1] = p0[1]; u0.u[2] = p0[2]; u0.u[3] = p0[3];
        b1[dt][0] = u0.v;
        v8s bk1 = {0,0,0,0,0,0,0,0};
        if (q == 0) {                 // k=32..63 -> m 32..39 valid, rest zero
          const unsigned* p1 = (const unsigned*)(xTw + r*42 + 32);
          v8u u1;
          u1.u[0] = p1[0]; u1.u[1] = p1[1]; u1.u[2] = p1[2]; u1.u[3] = p1[3];
          bk1 = u1.v;
        }
        b1[dt][1] = bk1;
      }
    }
    // ---- GEMM1: V = sNT .* (A^T x) ----
    v8s a1[3][2];
    #pragma unroll
    for (int nt = 0; nt < 3; ++nt)
      #pragma unroll
      for (int ks = 0; ks < 2; ++ks)
        a1[nt][ks] = *(const v8s*)(A1pk + (((t*3 + nt)*2 + ks) << 9) + lane*8);
    #pragma unroll
    for (int nt = 0; nt < 3; ++nt) {
      #pragma unroll
      for (int dt = 0; dt < 4; ++dt) {
        v4f acc = {0.f, 0.f, 0.f, 0.f};
        acc = __builtin_amdgcn_mfma_f32_16x16x32_bf16(a1[nt][0], b1[dt][0], acc, 0, 0, 0);
        acc = __builtin_amdgcn_mfma_f32_16x16x32_bf16(a1[nt][1], b1[dt][1], acc, 0, 0, 0);
        const int d = dt*16 + l15;
        const float4 sv = *(const float4*)(sNT + (t*64 + d)*40 + nt*16 + q*4);
        #pragma unroll
        for (int r = 0; r < 4; ++r) {
          const int n = nt*16 + q*4 + r;
          if (n < NB) Vw[n*72 + d] = f2b(acc[r]*sv[r]);
        }
      }
    }
    // ---- GEMM2: h' = [U|V] x W2 + bias -> hLg (d-major, uint2 packed) ----
    v8s af[3][4];
    #pragma unroll
    for (int nt = 0; nt < 3; ++nt) {
      const unsigned short* rowU = Uw + (nt*16 + l15)*72;
      const unsigned short* rowV = Vw + (nt*16 + l15)*72;
      af[nt][0] = *(const v8s*)(rowU + q*8);
      af[nt][1] = *(const v8s*)(rowU + 32 + q*8);
      af[nt][2] = *(const v8s*)(rowV + q*8);
      af[nt][3] = *(const v8s*)(rowV + 32 + q*8);
    }
    unsigned short* hLb = hLg + ((size_t)b*2 + t)*2560;
    #pragma unroll
    for (int dt = 0; dt < 4; ++dt) {
      v4f a2[3] = {{0,0,0,0},{0,0,0,0},{0,0,0,0}};
      #pragma unroll
      for (int ks = 0; ks < 4; ++ks) {
        const v8s w2k = *(const v8s*)(W2pk + ((t*16 + ks*4 + dt) << 9) + lane*8);
        #pragma unroll
        for (int nt = 0; nt < 3; ++nt)
          a2[nt] = __builtin_amdgcn_mfma_f32_16x16x32_bf16(af[nt][ks], w2k, a2[nt], 0, 0, 0);
      }
      const int d = dt*16 + l15;
      #pragma unroll
      for (int nt = 0; nt < 3; ++nt) {
        const int n0 = nt*16 + q*4;
        if (n0 < NB) {
          const float4 bv = *(const float4*)(bias2T + (t*64 + d)*40 + n0);
          uint2 pr;
          pr.x = pk2(a2[nt][0] + bv.x, a2[nt][1] + bv.y);
          pr.y = pk2(a2[nt][2] + bv.z, a2[nt][3] + bv.w);
          *(uint2*)(hLb + d*40 + n0) = pr;
        }
      }
    }
  }
}

// kernelB: 16 batches/block, 8 waves. GEMM3 (all 16 B-cols valid, Gpk read once
// per block), block softmax, then vectorized pool (thread = (b,t,d-quad),
// 20 contiguous uint4 loads from d-major hLg).
__global__ __launch_bounds__(512) void kernelB(
    const unsigned short* __restrict__ hLg, const unsigned short* __restrict__ Gpk,
    const float* __restrict__ gate_b, float* __restrict__ out)
{
  __shared__ float pj[8 * 48 * 17];   // (w*48 + j)*17 + b
  __shared__ float wgt[2 * 16 * NB];  // [t][b][n]

  const int tid = threadIdx.x;
  const int w = tid >> 6, lane = tid & 63;
  const int l = lane & 15, q = lane >> 4;
  const int b0 = blockIdx.x * 16;

  v4f ac[2][3];
  #pragma unroll
  for (int t = 0; t < 2; ++t)
    #pragma unroll
    for (int jt = 0; jt < 3; ++jt)
      ac[t][jt] = (v4f){0.f, 0.f, 0.f, 0.f};

  const unsigned short* hb = hLg + (size_t)(b0 + l) * 2 * 2560 + q * 8;
  int kt = w;
  v8s g0 = *(const v8s*)(Gpk + ((kt*3+0) << 9) + lane*8);
  v8s g1 = *(const v8s*)(Gpk + ((kt*3+1) << 9) + lane*8);
  v8s g2 = *(const v8s*)(Gpk + ((kt*3+2) << 9) + lane*8);
  v8s bf0 = *(const v8s*)(hb + kt*32);
  v8s bf1 = *(const v8s*)(hb + 2560 + kt*32);
  #pragma unroll
  for (int i = 0; i < 10; ++i) {
    const int ktn = kt + 8;
    v8s ng0, ng1, ng2, nbf0, nbf1;
    if (i < 9) {
      ng0  = *(const v8s*)(Gpk + ((ktn*3+0) << 9) + lane*8);
      ng1  = *(const v8s*)(Gpk + ((ktn*3+1) << 9) + lane*8);
      ng2  = *(const v8s*)(Gpk + ((ktn*3+2) << 9) + lane*8);
      nbf0 = *(const v8s*)(hb + ktn*32);
      nbf1 = *(const v8s*)(hb + 2560 + ktn*32);
    }
    ac[0][0] = __builtin_amdgcn_mfma_f32_16x16x32_bf16(g0, bf0, ac[0][0], 0, 0, 0);
    ac[0][1] = __builtin_amdgcn_mfma_f32_16x16x32_bf16(g1, bf0, ac[0][1], 0, 0, 0);
    ac[0][2] = __builtin_amdgcn_mfma_f32_16x16x32_bf16(g2, bf0, ac[0][2], 0, 0, 0);
    ac[1][0] = __builtin_amdgcn_mfma_f32_16x16x32_bf16(g0, bf1, ac[1][0], 0, 0, 0);
    ac[1][1] = __builtin_amdgcn_mfma_f32_16x16x32_bf16(g1, bf1, ac[1][1], 0, 0, 0);
    ac[1][2] = __builtin_amdgcn_mfma_f32_16x16x32_bf16(g2, bf1, ac[1][2], 0, 0, 0);
    g0 = ng0; g1 = ng1; g2 = ng2; bf0 = nbf0; bf1 = nbf1;
    kt = ktn;
  }

  #pragma unroll
  for (int t = 0; t < 2; ++t) {
    if (t) __syncthreads();   // pj reuse: t=0 softmax reads done first
    #pragma unroll
    for (int jt = 0; jt < 3; ++jt)
      #pragma unroll
      for (int r = 0; r < 4; ++r)
        pj[(w*48 + jt*16 + q*4 + r)*17 + l] = ac[t][jt][r];
    __syncthreads();
    // softmax: wave w handles batches w*2, w*2+1; lane = j
    #pragma unroll
    for (int hb2 = 0; hb2 < 2; ++hb2) {
      const int bb = w*2 + hb2;
      float v = -3.0e38f;
      if (lane < NB) {
        v = gate_b[lane];
        #pragma unroll
        for (int w8 = 0; w8 < 8; ++w8) v += pj[(w8*48 + lane)*17 + bb];
      }
      float mx = v;
      #pragma unroll
      for (int m = 1; m < 64; m <<= 1) mx = fmaxf(mx, __shfl_xor(mx, m));
      const float e = (lane < NB) ? __expf(v - mx) : 0.f;
      float es = e;
      #pragma unroll
      for (int m = 1; m < 64; m <<= 1) es += __shfl_xor(es, m);
      if (lane < NB) wgt[(t*16 + bb)*NB + lane] = e / es;
    }
  }
  __syncthreads();
  // ---- pool: thread = (b, t, d-quad); 160 contiguous shorts = 20 uint4 ----
  {
    const int bb = tid >> 5, t = (tid >> 4) & 1, d0 = (tid & 15) * 4;
    const uint4* hp4 = (const uint4*)(hLg + ((size_t)(b0 + bb)*2 + t)*2560 + d0*40);
    const float* wb = wgt + (t*16 + bb)*NB;
    float s[4] = {0.f, 0.f, 0.f, 0.f};
    #pragma unroll
    for (int k = 0; k < 20; ++k) {
      const uint4 rr = hp4[k];
      const int e0 = k*8;
      s[(e0+0)/40] += blo(rr.x)*wb[(e0+0)%40]; s[(e0+1)/40] += bhi(rr.x)*wb[(e0+1)%40];
      s[(e0+2)/40] += blo(rr.y)*wb[(e0+2)%40]; s[(e0+3)/40] += bhi(rr.y)*wb[(e0+3)%40];
      s[(e0+4)/40] += blo(rr.z)*wb[(e0+4)%40]; s[(e0+5)/40] += bhi(rr.z)*wb[(e0+5)%40];
      s[(e0+6)/40] += blo(rr.w)*wb[(e0+6)%40]; s[(e0+7)/40] += bhi(rr.w)*wb[(e0+7)%40];
    }
    float4 ov = make_float4(s[0], s[1], s[2], s[3]);
    *(float4*)(out + ((size_t)(b0 + bb)*2 + t)*64 + d0) = ov;
  }
}

extern "C" void kernel_launch(void* const* d_in, const int* in_sizes, int n_in,
                              void* d_out, int out_size, void* d_ws, size_t ws_size,
                              hipStream_t stream) {
  const float* x        = (const float*)d_in[0];
  const float* masker   = (const float*)d_in[1];
  const float* ln_gamma = (const float*)d_in[2];
  const float* ln_beta  = (const float*)d_in[3];
  const float* gnn_w    = (const float*)d_in[4];
  const float* gnn_b    = (const float*)d_in[5];
  const float* bn_gamma = (const float*)d_in[6];
  const float* bn_beta  = (const float*)d_in[7];
  const float* bn_mean  = (const float*)d_in[8];
  const float* bn_var   = (const float*)d_in[9];
  const float* gate_w   = (const float*)d_in[10];
  const float* gate_b   = (const float*)d_in[11];
  float* out = (float*)d_out;

  char* ws = (char*)d_ws;
  unsigned short* A1pk   = (unsigned short*)(ws + 0);
  unsigned short* W2pk   = (unsigned short*)(ws + 12288);
  unsigned short* Gpk    = (unsigned short*)(ws + 45056);
  float*          s1     = (float*)(ws + 290816);
  float*          sNT    = (float*)(ws + 311296);
  float*          bias2T = (float*)(ws + 331904);
  unsigned short* hLg    = (unsigned short*)(ws + 352512);

  prep<<<64, 256, 0, stream>>>(masker, ln_gamma, ln_beta, gnn_w, gnn_b,
                               bn_gamma, bn_beta, bn_mean, bn_var, gate_w,
                               A1pk, W2pk, Gpk, s1, sNT, bias2T);
  kernelA<<<2048, 256, 0, stream>>>(x, A1pk, W2pk, s1, sNT, bias2T, hLg);
  kernelB<<<512, 512, 0, stream>>>(hLg, Gpk, gate_b, out);
}